// Round 6
// baseline (198.568 us; speedup 1.0000x reference)
//
#include <hip/hip_runtime.h>
#include <hip/hip_bf16.h>

// Problem constants
#define B_      8
#define N_      1024
#define DIM_    512
#define H_      8
#define DH_     64
#define INNER_  512
#define SCALE_  0.125f
#define LOG2E_  1.4426950408889634f

typedef __attribute__((ext_vector_type(8))) __bf16         bf16x8;
typedef __attribute__((ext_vector_type(8))) unsigned short ushort8;
typedef __attribute__((ext_vector_type(4))) float          f32x4;

union FragCast { ushort8 u; bf16x8 b; };
union FragU32  { unsigned int u[4]; bf16x8 b; };

__device__ inline bf16x8 ld_frag(const unsigned short* p) {
    FragCast f; f.u = *(const ushort8*)p; return f.b;
}

__device__ inline f32x4 mfma16(bf16x8 a, bf16x8 b, f32x4 c) {
    return __builtin_amdgcn_mfma_f32_16x16x32_bf16(a, b, c, 0, 0, 0);
}

__device__ inline float fexp2(float x) { return __builtin_amdgcn_exp2f(x); }

// round-to-nearest-even float -> bf16 bits
__device__ inline unsigned short f2bf(float x) {
    unsigned int u = __float_as_uint(x);
    unsigned int lsb = (u >> 16) & 1u;
    u += 0x7fffu + lsb;
    return (unsigned short)(u >> 16);
}

// truncating pack: (bf16(hi) << 16) | bf16(lo), one v_perm
__device__ inline unsigned int pack_bf2(float hi, float lo) {
    return __builtin_amdgcn_perm(__float_as_uint(hi), __float_as_uint(lo), 0x07060302u);
}

// async global->LDS, 16 bytes per lane (m97 pattern)
__device__ inline void gl_lds(const unsigned short* g, unsigned short* l) {
    __builtin_amdgcn_global_load_lds(
        (const __attribute__((address_space(1))) unsigned int*)g,
        (__attribute__((address_space(3))) unsigned int*)l, 16, 0, 0);
}

// ---------------------------------------------------------------------------
// K0: fp32 -> bf16 conversions, block-uniform region dispatch.
// ---------------------------------------------------------------------------
__global__ __launch_bounds__(256) void k_convert(
    const float* __restrict__ x, const float* __restrict__ lidar,
    const float* __restrict__ wqkv, const float* __restrict__ wmerge,
    const float* __restrict__ wout,
    unsigned short* __restrict__ x_bf, unsigned short* __restrict__ lid_bf,
    float* __restrict__ out_lidar,
    unsigned short* __restrict__ wqkv_bf, unsigned short* __restrict__ wm_bf,
    unsigned short* __restrict__ wout_bf)
{
    const int bx = blockIdx.x, tid = threadIdx.x;
    const float* src; unsigned short* dst; bool isLid = false; long base;
    if (bx < 1024)      { src = x;      dst = x_bf;    base = (long)bx * 1024; }
    else if (bx < 2048) { src = lidar;  dst = lid_bf;  base = (long)(bx - 1024) * 1024; isLid = true; }
    else if (bx < 2240) { src = wqkv;   dst = wqkv_bf; base = (long)(bx - 2048) * 1024; }
    else if (bx < 2304) { src = wout;   dst = wout_bf; base = (long)(bx - 2240) * 1024; }
    else                { src = wmerge; dst = wm_bf;   base = 0; }
    for (int k = 0; k < 4; k++) {
        long j = base + k * 256 + tid;
        float4 v = ((const float4*)src)[j];
        ushort4 o;
        o.x = f2bf(v.x); o.y = f2bf(v.y); o.z = f2bf(v.z); o.w = f2bf(v.w);
        ((ushort4*)dst)[j] = o;
        if (isLid) ((float4*)out_lidar)[j] = v;
    }
}

// ---------------------------------------------------------------------------
// K1: QKV GEMM, C = A * B^T, 128x128 tile, BK=64, XOR-swizzled async staging.
// Q,K thirds (n0 < 1024) -> qkv_bf[token][1536].
// V third  (n0 >= 1024)  -> vt[feature][token] in PV-interleaved token order
//   pp(t) = (t>>5)*32 + ((t>>2)&3)*8 + ((t>>4)&1)*4 + (t&3)
// ---------------------------------------------------------------------------
__global__ __launch_bounds__(256) void k_gemm_qkv(
    const unsigned short* __restrict__ A, const unsigned short* __restrict__ Bm,
    unsigned short* __restrict__ C, unsigned short* __restrict__ vt,
    int M, int Nd, int K)
{
    __shared__ unsigned short sA[128 * 64];
    __shared__ unsigned short sB[128 * 64];
    const int tid  = threadIdx.x;
    const int lane = tid & 63, wave = tid >> 6;
    const int q = lane >> 4, l15 = lane & 15, l7 = l15 & 7;
    const int xq0 = (q ^ l7) << 3, xq4 = ((q + 4) ^ l7) << 3;
    const int m0 = blockIdx.x * 128, n0 = blockIdx.y * 128;
    const int wm = (wave >> 1) * 64, wn = (wave & 1) * 64;
    f32x4 acc[4][4] = {};

    for (int k0 = 0; k0 < K; k0 += 64) {
        __syncthreads();
        for (int i = 0; i < 4; i++) {
            int c = i * 256 + tid;
            int row = c >> 3;
            int gcol = ((c & 7) ^ (row & 7)) << 3;
            gl_lds(&A[(long)(m0 + row) * K + k0 + gcol], &sA[c * 8]);
            gl_lds(&Bm[(long)(n0 + row) * K + k0 + gcol], &sB[c * 8]);
        }
        __syncthreads();
        for (int kk = 0; kk < 2; kk++) {
            const int xx = kk ? xq4 : xq0;
            bf16x8 af[4], bfr[4];
            for (int i = 0; i < 4; i++)
                af[i]  = ld_frag(&sA[(wm + i * 16 + l15) * 64 + xx]);
            for (int i = 0; i < 4; i++)
                bfr[i] = ld_frag(&sB[(wn + i * 16 + l15) * 64 + xx]);
            for (int mi = 0; mi < 4; mi++)
                for (int ni = 0; ni < 4; ni++)
                    acc[mi][ni] = mfma16(af[mi], bfr[ni], acc[mi][ni]);
        }
    }
    if (n0 < 1024) {
        for (int mi = 0; mi < 4; mi++)
            for (int ni = 0; ni < 4; ni++)
                for (int r = 0; r < 4; r++) {
                    int row = m0 + wm + mi * 16 + q * 4 + r;
                    int col = n0 + wn + ni * 16 + l15;
                    C[(long)row * Nd + col] = f2bf(acc[mi][ni][r]);
                }
    } else {
        for (int mi = 0; mi < 4; mi++) {
            int pp0 = (mi >> 1) * 32 + q * 8 + (mi & 1) * 4;
            long tbase = m0 + wm + pp0;
            for (int ni = 0; ni < 4; ni++) {
                int f = (n0 - 1024) + wn + ni * 16 + l15;
                ushort4 o4;
                o4.x = f2bf(acc[mi][ni][0]); o4.y = f2bf(acc[mi][ni][1]);
                o4.z = f2bf(acc[mi][ni][2]); o4.w = f2bf(acc[mi][ni][3]);
                *(ushort4*)&vt[(long)f * (B_ * N_) + tbase] = o4;
            }
        }
    }
}

// ---------------------------------------------------------------------------
// K3: out GEMM (fp32 out + bias), 128x64 tile, BK=64, swizzled async staging.
// ---------------------------------------------------------------------------
__global__ __launch_bounds__(256) void k_gemm_out(
    const unsigned short* __restrict__ A, const unsigned short* __restrict__ Bm,
    const float* __restrict__ bias, float* __restrict__ C, int M, int Nd, int K)
{
    __shared__ unsigned short sA[128 * 64];
    __shared__ unsigned short sB[64 * 64];
    const int tid  = threadIdx.x;
    const int lane = tid & 63, wave = tid >> 6;
    const int q = lane >> 4, l15 = lane & 15, l7 = l15 & 7;
    const int xq0 = (q ^ l7) << 3, xq4 = ((q + 4) ^ l7) << 3;
    const int m0 = blockIdx.x * 128, n0 = blockIdx.y * 64;
    const int wm = (wave >> 1) * 64, wn = (wave & 1) * 32;
    f32x4 acc[4][2] = {};

    for (int k0 = 0; k0 < K; k0 += 64) {
        __syncthreads();
        for (int i = 0; i < 4; i++) {
            int c = i * 256 + tid;
            int row = c >> 3;
            int gcol = ((c & 7) ^ (row & 7)) << 3;
            gl_lds(&A[(long)(m0 + row) * K + k0 + gcol], &sA[c * 8]);
            if (i < 2)
                gl_lds(&Bm[(long)(n0 + row) * K + k0 + gcol], &sB[c * 8]);
        }
        __syncthreads();
        for (int kk = 0; kk < 2; kk++) {
            const int xx = kk ? xq4 : xq0;
            bf16x8 af[4], bfr[2];
            for (int i = 0; i < 4; i++)
                af[i]  = ld_frag(&sA[(wm + i * 16 + l15) * 64 + xx]);
            for (int i = 0; i < 2; i++)
                bfr[i] = ld_frag(&sB[(wn + i * 16 + l15) * 64 + xx]);
            for (int mi = 0; mi < 4; mi++)
                for (int ni = 0; ni < 2; ni++)
                    acc[mi][ni] = mfma16(af[mi], bfr[ni], acc[mi][ni]);
        }
    }
    for (int mi = 0; mi < 4; mi++)
        for (int ni = 0; ni < 2; ni++)
            for (int r = 0; r < 4; r++) {
                int row = m0 + wm + mi * 16 + q * 4 + r;
                int col = n0 + wn + ni * 16 + l15;
                C[(long)row * Nd + col] = acc[mi][ni][r] + bias[col];
            }
}

// ---------------------------------------------------------------------------
// K2: fused flash attention, 64-row i-tiles (1 q-set/wave, 4 blocks/CU for
// latency hiding). Grid (x=bh, y=itile) so all blocks sharing one (b,h)'s
// K/lid/V tiles land on the same XCD (bh&7 slot) -> L2-resident tiles.
// Sweep 1: lidar softmax denominators. Sweep 2: blended flash + packed PV.
// All tiles XOR-swizzled, all staging via global_load_lds.
// ---------------------------------------------------------------------------
__global__ __launch_bounds__(256) void k_flash(
    const unsigned short* __restrict__ qkv_bf, const unsigned short* __restrict__ lid_bf,
    const unsigned short* __restrict__ vt,
    const unsigned short* __restrict__ wm_bf, const float* __restrict__ b_merge,
    const float* __restrict__ conv_w, const float* __restrict__ conv_b,
    unsigned short* __restrict__ tmp_bf)
{
    __shared__ unsigned short sK[64 * 64];       // [j][d] swizzled
    __shared__ unsigned short sLid[64 * 64];     // [j][d] swizzled
    __shared__ unsigned short sVT[64 * 64];      // [d][interleaved tok] swizzled
    __shared__ unsigned short sO[4 * 16 * 72];   // per-wave O tile [i][d]
    __shared__ float sRS[4][16];

    const int tid = threadIdx.x, lane = tid & 63, wave = tid >> 6;
    const int q = lane >> 4, l15 = lane & 15, l7 = l15 & 7;
    const int xq0 = (q ^ l7) << 3, xq4 = ((q + 4) ^ l7) << 3;
    const int bh = blockIdx.x, itile = blockIdx.y;   // x=bh for XCD locality
    const int b = bh >> 3, h = bh & 7;
    const int i0w = itile * 64 + wave * 16;
    const long rowB = (long)b * N_;
    const int colh = h * DH_;
    const float k0c = conv_w[0] * SCALE_ * LOG2E_;
    const float k2c = conv_b[0] * LOG2E_;
    const float c1L = conv_w[1] * LOG2E_;
    const float sc = SCALE_ * LOG2E_;

    // Q / lid query fragments (B-operand: row i = l15, contiguous d)
    bf16x8 qf[2], lfq[2];
    for (int ks = 0; ks < 2; ks++) {
        qf[ks]  = ld_frag(&qkv_bf[(rowB + i0w + l15) * 1536 + colh + ks * 32 + q * 8]);
        lfq[ks] = ld_frag(&lid_bf[(rowB + i0w + l15) * INNER_ + colh + ks * 32 + q * 8]);
    }

    // ---- sweep 1: lidar softmax denominator for query row i = l15 ----
    float rsl = 0.f;
    for (int j0 = 0; j0 < N_; j0 += 64) {
        __syncthreads();
        for (int i = 0; i < 2; i++) {
            int c = i * 256 + tid;
            int row = c >> 3;
            int gcol = ((c & 7) ^ (row & 7)) << 3;
            gl_lds(&lid_bf[(rowB + j0 + row) * INNER_ + colh + gcol], &sLid[c * 8]);
        }
        __syncthreads();
        for (int ns = 0; ns < 4; ns++) {
            int rb = (ns * 16 + l15) * 64;
            f32x4 cv = {0.f, 0.f, 0.f, 0.f};
            cv = mfma16(ld_frag(&sLid[rb + xq0]), lfq[0], cv);
            cv = mfma16(ld_frag(&sLid[rb + xq4]), lfq[1], cv);
            for (int r = 0; r < 4; r++) rsl += fexp2(cv[r] * sc);
        }
    }
    rsl += __shfl_xor(rsl, 16);
    rsl += __shfl_xor(rsl, 32);
    const float k1 = c1L / rsl;

    // ---- sweep 2: blended flash ----
    float rs = 0.f;
    f32x4 o[4] = {};   // o[dt]: lane holds O[i = q*4+r][d = dt*16 + l15]

    for (int j0 = 0; j0 < N_; j0 += 64) {
        __syncthreads();
        for (int i = 0; i < 2; i++) {
            int c = i * 256 + tid;
            int row = c >> 3;
            int gcol = ((c & 7) ^ (row & 7)) << 3;
            gl_lds(&qkv_bf[(rowB + j0 + row) * 1536 + 512 + colh + gcol], &sK[c * 8]);
            gl_lds(&lid_bf[(rowB + j0 + row) * INNER_ + colh + gcol], &sLid[c * 8]);
            gl_lds(&vt[(long)(colh + row) * (B_ * N_) + rowB + j0 + gcol], &sVT[c * 8]);
        }
        __syncthreads();

        for (int ns2 = 0; ns2 < 2; ns2++) {
            FragU32 fa;
            for (int h2 = 0; h2 < 2; h2++) {
                int ns = ns2 * 2 + h2;
                int rb = (ns * 16 + l15) * 64;
                // S^T: lane holds S[i=l15][j = ns*16 + q*4 + r]
                f32x4 a = {0.f, 0.f, 0.f, 0.f};
                a = mfma16(ld_frag(&sK[rb + xq0]), qf[0], a);
                a = mfma16(ld_frag(&sK[rb + xq4]), qf[1], a);
                f32x4 cv = {0.f, 0.f, 0.f, 0.f};
                cv = mfma16(ld_frag(&sLid[rb + xq0]), lfq[0], cv);
                cv = mfma16(ld_frag(&sLid[rb + xq4]), lfq[1], cv);
                float pv[4];
                for (int r = 0; r < 4; r++) {
                    float els = fexp2(cv[r] * sc);
                    float t = fmaf(k0c, a[r], k2c);
                    t = fmaf(k1, els, t);
                    pv[r] = fexp2(t);
                    rs += pv[r];
                }
                fa.u[h2 * 2 + 0] = pack_bf2(pv[1], pv[0]);
                fa.u[h2 * 2 + 1] = pack_bf2(pv[3], pv[2]);
            }
            // PV over 32 tokens (interleaved vt layout, swizzled chunks)
            for (int dt = 0; dt < 4; dt++) {
                int vrow = dt * 16 + l15;
                bf16x8 vb = ld_frag(&sVT[vrow * 64 + (((ns2 * 4 + q) ^ l7) << 3)]);
                o[dt] = mfma16(fa.b, vb, o[dt]);
            }
        }
    }

    // ---- epilogue: normalize + fused per-head merge ----
    rs += __shfl_xor(rs, 16);
    rs += __shfl_xor(rs, 32);
    if (q == 0) sRS[wave][l15] = rs;          // wave-private, in-order
    float invr[4];
    for (int r = 0; r < 4; r++) invr[r] = 1.f / sRS[wave][q * 4 + r];

    unsigned short* pO = &sO[wave * 16 * 72];
    for (int dt = 0; dt < 4; dt++)
        for (int r = 0; r < 4; r++)
            pO[(q * 4 + r) * 72 + dt * 16 + l15] = f2bf(o[dt][r] * invr[r]);

    f32x4 mo[4] = {};
    for (int ks = 0; ks < 2; ks++) {
        bf16x8 af = ld_frag(&pO[l15 * 72 + ks * 32 + q * 8]);
        for (int ns = 0; ns < 4; ns++) {
            bf16x8 wf = ld_frag(&wm_bf[(ns * 16 + l15) * 64 + ks * 32 + q * 8]);
            mo[ns] = mfma16(af, wf, mo[ns]);
        }
    }
    for (int ns = 0; ns < 4; ns++) {
        float bm = b_merge[ns * 16 + l15];
        for (int r = 0; r < 4; r++) {
            long row = rowB + i0w + q * 4 + r;
            tmp_bf[row * INNER_ + colh + ns * 16 + l15] = f2bf(mo[ns][r] + bm);
        }
    }
}

// ---------------------------------------------------------------------------
extern "C" void kernel_launch(void* const* d_in, const int* in_sizes, int n_in,
                              void* d_out, int out_size, void* d_ws, size_t ws_size,
                              hipStream_t stream) {
    const float* x       = (const float*)d_in[0];
    const float* lidar   = (const float*)d_in[1];
    const float* w_qkv   = (const float*)d_in[2];
    const float* w_merge = (const float*)d_in[3];
    const float* b_merge = (const float*)d_in[4];
    const float* w_out   = (const float*)d_in[5];
    const float* b_out   = (const float*)d_in[6];
    const float* conv_w  = (const float*)d_in[7];
    const float* conv_b  = (const float*)d_in[8];

    float* out0      = (float*)d_out;                      // [B,N,DIM]
    float* out_lidar = out0 + (long)B_ * N_ * INNER_;      // [B,N,INNER]

    size_t off = 0;
    auto carve = [&](size_t bytes) {
        void* p = (char*)d_ws + off;
        off += (bytes + 255) & ~(size_t)255;
        return p;
    };
    unsigned short* qkv_bf  = (unsigned short*)carve((size_t)B_ * N_ * 3 * INNER_ * 2);
    unsigned short* lid_bf  = (unsigned short*)carve((size_t)B_ * N_ * INNER_ * 2);
    unsigned short* x_bf    = (unsigned short*)carve((size_t)B_ * N_ * DIM_ * 2);
    unsigned short* wqkv_bf = (unsigned short*)carve((size_t)3 * INNER_ * DIM_ * 2);
    unsigned short* wout_bf = (unsigned short*)carve((size_t)DIM_ * INNER_ * 2);
    unsigned short* wm_bf   = (unsigned short*)carve((size_t)DH_ * DH_ * 2);
    unsigned short* tmp_bf  = (unsigned short*)carve((size_t)B_ * N_ * INNER_ * 2);
    unsigned short* vt_bf   = (unsigned short*)carve((size_t)INNER_ * B_ * N_ * 2);

    k_convert<<<2305, 256, 0, stream>>>(x, lidar, w_qkv, w_merge, w_out,
                                        x_bf, lid_bf, out_lidar,
                                        wqkv_bf, wm_bf, wout_bf);

    k_gemm_qkv<<<dim3(64, 12), 256, 0, stream>>>(
        x_bf, wqkv_bf, qkv_bf, vt_bf, B_ * N_, 3 * INNER_, DIM_);

    k_flash<<<dim3(64, 16), 256, 0, stream>>>(
        qkv_bf, lid_bf, vt_bf, wm_bf, b_merge, conv_w, conv_b, tmp_bf);

    k_gemm_out<<<dim3(64, 8), 256, 0, stream>>>(
        tmp_bf, wout_bf, b_out, out0, B_ * N_, DIM_, INNER_);
}

// Round 7
// 193.798 us; speedup vs baseline: 1.0246x; 1.0246x over previous
//
#include <hip/hip_runtime.h>
#include <hip/hip_bf16.h>

// Problem constants
#define B_      8
#define N_      1024
#define DIM_    512
#define H_      8
#define DH_     64
#define INNER_  512
#define SCALE_  0.125f
#define LOG2E_  1.4426950408889634f

typedef __attribute__((ext_vector_type(8))) __bf16         bf16x8;
typedef __attribute__((ext_vector_type(8))) unsigned short ushort8;
typedef __attribute__((ext_vector_type(4))) float          f32x4;

union FragCast { ushort8 u; bf16x8 b; };
union FragU32  { unsigned int u[4]; bf16x8 b; };

__device__ inline bf16x8 ld_frag(const unsigned short* p) {
    FragCast f; f.u = *(const ushort8*)p; return f.b;
}

__device__ inline f32x4 mfma16(bf16x8 a, bf16x8 b, f32x4 c) {
    return __builtin_amdgcn_mfma_f32_16x16x32_bf16(a, b, c, 0, 0, 0);
}

__device__ inline float fexp2(float x) { return __builtin_amdgcn_exp2f(x); }

// round-to-nearest-even float -> bf16 bits
__device__ inline unsigned short f2bf(float x) {
    unsigned int u = __float_as_uint(x);
    unsigned int lsb = (u >> 16) & 1u;
    u += 0x7fffu + lsb;
    return (unsigned short)(u >> 16);
}

// truncating pack: (bf16(hi) << 16) | bf16(lo), one v_perm
__device__ inline unsigned int pack_bf2(float hi, float lo) {
    return __builtin_amdgcn_perm(__float_as_uint(hi), __float_as_uint(lo), 0x07060302u);
}

// async global->LDS, 16 bytes per lane (m97 pattern)
__device__ inline void gl_lds(const unsigned short* g, unsigned short* l) {
    __builtin_amdgcn_global_load_lds(
        (const __attribute__((address_space(1))) unsigned int*)g,
        (__attribute__((address_space(3))) unsigned int*)l, 16, 0, 0);
}

// ---------------------------------------------------------------------------
// K0: fp32 -> bf16 conversions, block-uniform region dispatch.
// ---------------------------------------------------------------------------
__global__ __launch_bounds__(256) void k_convert(
    const float* __restrict__ x, const float* __restrict__ lidar,
    const float* __restrict__ wqkv, const float* __restrict__ wmerge,
    const float* __restrict__ wout,
    unsigned short* __restrict__ x_bf, unsigned short* __restrict__ lid_bf,
    float* __restrict__ out_lidar,
    unsigned short* __restrict__ wqkv_bf, unsigned short* __restrict__ wm_bf,
    unsigned short* __restrict__ wout_bf)
{
    const int bx = blockIdx.x, tid = threadIdx.x;
    const float* src; unsigned short* dst; bool isLid = false; long base;
    if (bx < 1024)      { src = x;      dst = x_bf;    base = (long)bx * 1024; }
    else if (bx < 2048) { src = lidar;  dst = lid_bf;  base = (long)(bx - 1024) * 1024; isLid = true; }
    else if (bx < 2240) { src = wqkv;   dst = wqkv_bf; base = (long)(bx - 2048) * 1024; }
    else if (bx < 2304) { src = wout;   dst = wout_bf; base = (long)(bx - 2240) * 1024; }
    else                { src = wmerge; dst = wm_bf;   base = 0; }
    for (int k = 0; k < 4; k++) {
        long j = base + k * 256 + tid;
        float4 v = ((const float4*)src)[j];
        ushort4 o;
        o.x = f2bf(v.x); o.y = f2bf(v.y); o.z = f2bf(v.z); o.w = f2bf(v.w);
        ((ushort4*)dst)[j] = o;
        if (isLid) ((float4*)out_lidar)[j] = v;
    }
}

// ---------------------------------------------------------------------------
// K1: QKV GEMM, C = A * B^T, 128x128 tile, BK=64, XOR-swizzled async staging.
// Q,K thirds (n0 < 1024) -> qkv_bf[token][1536] (coalesced C-writes).
// V third  (n0 >= 1024)  -> vt[feature][token], PV-interleaved token order
//   p(t) = (t>>5)*32 + ((t>>2)&3)*8 + ((t>>4)&1)*4 + (t&3)
// assembled through LDS so global writes are coalesced 16B rows (the old
// direct scatter was 8B stores at 16KB stride -> write-allocate blowup).
// ---------------------------------------------------------------------------
__global__ __launch_bounds__(256) void k_gemm_qkv(
    const unsigned short* __restrict__ A, const unsigned short* __restrict__ Bm,
    unsigned short* __restrict__ C, unsigned short* __restrict__ vt,
    int M, int Nd, int K)
{
    __shared__ unsigned short sMem[128 * 136];   // sA|sB in main loop; sT in V epilogue
    unsigned short* sA = sMem;                   // 128*64
    unsigned short* sB = sMem + 128 * 64;        // 128*64
    const int tid  = threadIdx.x;
    const int lane = tid & 63, wave = tid >> 6;
    const int q = lane >> 4, l15 = lane & 15, l7 = l15 & 7;
    const int xq0 = (q ^ l7) << 3, xq4 = ((q + 4) ^ l7) << 3;
    const int m0 = blockIdx.x * 128, n0 = blockIdx.y * 128;
    const int wm = (wave >> 1) * 64, wn = (wave & 1) * 64;
    f32x4 acc[4][4] = {};

    for (int k0 = 0; k0 < K; k0 += 64) {
        __syncthreads();
        for (int i = 0; i < 4; i++) {
            int c = i * 256 + tid;
            int row = c >> 3;
            int gcol = ((c & 7) ^ (row & 7)) << 3;
            gl_lds(&A[(long)(m0 + row) * K + k0 + gcol], &sA[c * 8]);
            gl_lds(&Bm[(long)(n0 + row) * K + k0 + gcol], &sB[c * 8]);
        }
        __syncthreads();
        for (int kk = 0; kk < 2; kk++) {
            const int xx = kk ? xq4 : xq0;
            bf16x8 af[4], bfr[4];
            for (int i = 0; i < 4; i++)
                af[i]  = ld_frag(&sA[(wm + i * 16 + l15) * 64 + xx]);
            for (int i = 0; i < 4; i++)
                bfr[i] = ld_frag(&sB[(wn + i * 16 + l15) * 64 + xx]);
            for (int mi = 0; mi < 4; mi++)
                for (int ni = 0; ni < 4; ni++)
                    acc[mi][ni] = mfma16(af[mi], bfr[ni], acc[mi][ni]);
        }
    }
    if (n0 < 1024) {
        for (int mi = 0; mi < 4; mi++)
            for (int ni = 0; ni < 4; ni++)
                for (int r = 0; r < 4; r++) {
                    int row = m0 + wm + mi * 16 + q * 4 + r;
                    int col = n0 + wn + ni * 16 + l15;
                    C[(long)row * Nd + col] = f2bf(acc[mi][ni][r]);
                }
    } else {
        // ---- V epilogue: acc -> LDS sT[f][tok] (stride 136) -> coalesced vt ----
        __syncthreads();   // all waves done reading sA/sB
        for (int mi = 0; mi < 4; mi++) {
            int t0 = wm + mi * 16 + q * 4;
            for (int ni = 0; ni < 4; ni++) {
                int f = wn + ni * 16 + l15;
                ushort4 o4;
                o4.x = f2bf(acc[mi][ni][0]); o4.y = f2bf(acc[mi][ni][1]);
                o4.z = f2bf(acc[mi][ni][2]); o4.w = f2bf(acc[mi][ni][3]);
                *(ushort4*)&sMem[f * 136 + t0] = o4;   // 8B store, 2-way alias = free
            }
        }
        __syncthreads();
        // each output ushort8 group (8 interleaved positions) = two source
        // ushort4 runs at t = base and t = base+16  (inverse of p(t))
        const long fb = (long)(n0 - 1024) * (B_ * N_) + m0;
        for (int i = 0; i < 8; i++) {
            int g = i * 256 + tid;              // 128 f x 16 groups
            int f = g >> 4, grp = g & 15;
            int base = (grp >> 2) * 32 + (grp & 3) * 4;
            ushort4 a4 = *(const ushort4*)&sMem[f * 136 + base];
            ushort4 b4 = *(const ushort4*)&sMem[f * 136 + base + 16];
            ushort8 o8 = {a4.x, a4.y, a4.z, a4.w, b4.x, b4.y, b4.z, b4.w};
            *(ushort8*)&vt[fb + (long)f * (B_ * N_) + grp * 8] = o8;
        }
    }
}

// ---------------------------------------------------------------------------
// K3: out GEMM (fp32 out + bias), 128x64 tile, BK=64, swizzled async staging.
// ---------------------------------------------------------------------------
__global__ __launch_bounds__(256) void k_gemm_out(
    const unsigned short* __restrict__ A, const unsigned short* __restrict__ Bm,
    const float* __restrict__ bias, float* __restrict__ C, int M, int Nd, int K)
{
    __shared__ unsigned short sA[128 * 64];
    __shared__ unsigned short sB[64 * 64];
    const int tid  = threadIdx.x;
    const int lane = tid & 63, wave = tid >> 6;
    const int q = lane >> 4, l15 = lane & 15, l7 = l15 & 7;
    const int xq0 = (q ^ l7) << 3, xq4 = ((q + 4) ^ l7) << 3;
    const int m0 = blockIdx.x * 128, n0 = blockIdx.y * 64;
    const int wm = (wave >> 1) * 64, wn = (wave & 1) * 32;
    f32x4 acc[4][2] = {};

    for (int k0 = 0; k0 < K; k0 += 64) {
        __syncthreads();
        for (int i = 0; i < 4; i++) {
            int c = i * 256 + tid;
            int row = c >> 3;
            int gcol = ((c & 7) ^ (row & 7)) << 3;
            gl_lds(&A[(long)(m0 + row) * K + k0 + gcol], &sA[c * 8]);
            if (i < 2)
                gl_lds(&Bm[(long)(n0 + row) * K + k0 + gcol], &sB[c * 8]);
        }
        __syncthreads();
        for (int kk = 0; kk < 2; kk++) {
            const int xx = kk ? xq4 : xq0;
            bf16x8 af[4], bfr[2];
            for (int i = 0; i < 4; i++)
                af[i]  = ld_frag(&sA[(wm + i * 16 + l15) * 64 + xx]);
            for (int i = 0; i < 2; i++)
                bfr[i] = ld_frag(&sB[(wn + i * 16 + l15) * 64 + xx]);
            for (int mi = 0; mi < 4; mi++)
                for (int ni = 0; ni < 2; ni++)
                    acc[mi][ni] = mfma16(af[mi], bfr[ni], acc[mi][ni]);
        }
    }
    for (int mi = 0; mi < 4; mi++)
        for (int ni = 0; ni < 2; ni++)
            for (int r = 0; r < 4; r++) {
                int row = m0 + wm + mi * 16 + q * 4 + r;
                int col = n0 + wn + ni * 16 + l15;
                C[(long)row * Nd + col] = acc[mi][ni][r] + bias[col];
            }
}

// ---------------------------------------------------------------------------
// K2: fused flash attention, 64-row i-tiles, XCD-local grid (x=bh).
// Staging addresses strength-reduced to running pointers (+const stride/iter).
// ---------------------------------------------------------------------------
__global__ __launch_bounds__(256) void k_flash(
    const unsigned short* __restrict__ qkv_bf, const unsigned short* __restrict__ lid_bf,
    const unsigned short* __restrict__ vt,
    const unsigned short* __restrict__ wm_bf, const float* __restrict__ b_merge,
    const float* __restrict__ conv_w, const float* __restrict__ conv_b,
    unsigned short* __restrict__ tmp_bf)
{
    __shared__ unsigned short sK[64 * 64];       // [j][d] swizzled
    __shared__ unsigned short sLid[64 * 64];     // [j][d] swizzled
    __shared__ unsigned short sVT[64 * 64];      // [d][interleaved tok] swizzled
    __shared__ unsigned short sO[4 * 16 * 72];   // per-wave O tile [i][d]
    __shared__ float sRS[4][16];

    const int tid = threadIdx.x, lane = tid & 63, wave = tid >> 6;
    const int q = lane >> 4, l15 = lane & 15, l7 = l15 & 7;
    const int xq0 = (q ^ l7) << 3, xq4 = ((q + 4) ^ l7) << 3;
    const int bh = blockIdx.x, itile = blockIdx.y;   // x=bh for XCD locality
    const int b = bh >> 3, h = bh & 7;
    const int i0w = itile * 64 + wave * 16;
    const long rowB = (long)b * N_;
    const int colh = h * DH_;
    const float k0c = conv_w[0] * SCALE_ * LOG2E_;
    const float k2c = conv_b[0] * LOG2E_;
    const float c1L = conv_w[1] * LOG2E_;
    const float sc = SCALE_ * LOG2E_;

    // per-thread staging setup (constant across iterations)
    int c0i = tid, c1i = 256 + tid;
    int row0 = c0i >> 3, row1 = c1i >> 3;
    int gc0 = ((c0i & 7) ^ (row0 & 7)) << 3;
    int gc1 = ((c1i & 7) ^ (row1 & 7)) << 3;
    unsigned short* dK0 = &sK[c0i * 8];   unsigned short* dK1 = &sK[c1i * 8];
    unsigned short* dL0 = &sLid[c0i * 8]; unsigned short* dL1 = &sLid[c1i * 8];
    unsigned short* dV0 = &sVT[c0i * 8];  unsigned short* dV1 = &sVT[c1i * 8];
    const unsigned short* gK0 = &qkv_bf[(rowB + row0) * 1536 + 512 + colh + gc0];
    const unsigned short* gK1 = &qkv_bf[(rowB + row1) * 1536 + 512 + colh + gc1];
    const unsigned short* gL0 = &lid_bf[(rowB + row0) * INNER_ + colh + gc0];
    const unsigned short* gL1 = &lid_bf[(rowB + row1) * INNER_ + colh + gc1];
    const unsigned short* gV0 = &vt[(long)(colh + row0) * (B_ * N_) + rowB + gc0];
    const unsigned short* gV1 = &vt[(long)(colh + row1) * (B_ * N_) + rowB + gc1];

    // LDS fragment row bases (constant per lane)
    const unsigned short *sK_r[4], *sL_r[4];
    for (int ns = 0; ns < 4; ns++) {
        sK_r[ns] = &sK[(ns * 16 + l15) * 64];
        sL_r[ns] = &sLid[(ns * 16 + l15) * 64];
    }

    // Q / lid query fragments (B-operand: row i = l15, contiguous d)
    bf16x8 qf[2], lfq[2];
    for (int ks = 0; ks < 2; ks++) {
        qf[ks]  = ld_frag(&qkv_bf[(rowB + i0w + l15) * 1536 + colh + ks * 32 + q * 8]);
        lfq[ks] = ld_frag(&lid_bf[(rowB + i0w + l15) * INNER_ + colh + ks * 32 + q * 8]);
    }

    // ---- sweep 1: lidar softmax denominator for query row i = l15 ----
    float rsl = 0.f;
    {
        const unsigned short* p0 = gL0;
        const unsigned short* p1 = gL1;
        for (int j0 = 0; j0 < N_; j0 += 64) {
            __syncthreads();
            gl_lds(p0, dL0);
            gl_lds(p1, dL1);
            p0 += 64 * INNER_; p1 += 64 * INNER_;
            __syncthreads();
            for (int ns = 0; ns < 4; ns++) {
                f32x4 cv = {0.f, 0.f, 0.f, 0.f};
                cv = mfma16(ld_frag(sL_r[ns] + xq0), lfq[0], cv);
                cv = mfma16(ld_frag(sL_r[ns] + xq4), lfq[1], cv);
                for (int r = 0; r < 4; r++) rsl += fexp2(cv[r] * sc);
            }
        }
    }
    rsl += __shfl_xor(rsl, 16);
    rsl += __shfl_xor(rsl, 32);
    const float k1 = c1L / rsl;

    // ---- sweep 2: blended flash ----
    float rs = 0.f;
    f32x4 o[4] = {};   // o[dt]: lane holds O[i = q*4+r][d = dt*16 + l15]

    for (int j0 = 0; j0 < N_; j0 += 64) {
        __syncthreads();
        gl_lds(gK0, dK0); gl_lds(gK1, dK1);
        gl_lds(gL0, dL0); gl_lds(gL1, dL1);
        gl_lds(gV0, dV0); gl_lds(gV1, dV1);
        gK0 += 64 * 1536;  gK1 += 64 * 1536;
        gL0 += 64 * INNER_; gL1 += 64 * INNER_;
        gV0 += 64;          gV1 += 64;
        __syncthreads();

        for (int ns2 = 0; ns2 < 2; ns2++) {
            FragU32 fa;
            for (int h2 = 0; h2 < 2; h2++) {
                int ns = ns2 * 2 + h2;
                // S^T: lane holds S[i=l15][j = ns*16 + q*4 + r]
                f32x4 a = {0.f, 0.f, 0.f, 0.f};
                a = mfma16(ld_frag(sK_r[ns] + xq0), qf[0], a);
                a = mfma16(ld_frag(sK_r[ns] + xq4), qf[1], a);
                f32x4 cv = {0.f, 0.f, 0.f, 0.f};
                cv = mfma16(ld_frag(sL_r[ns] + xq0), lfq[0], cv);
                cv = mfma16(ld_frag(sL_r[ns] + xq4), lfq[1], cv);
                float pv[4];
                for (int r = 0; r < 4; r++) {
                    float els = fexp2(cv[r] * sc);
                    float t = fmaf(k0c, a[r], k2c);
                    t = fmaf(k1, els, t);
                    pv[r] = fexp2(t);
                    rs += pv[r];
                }
                fa.u[h2 * 2 + 0] = pack_bf2(pv[1], pv[0]);
                fa.u[h2 * 2 + 1] = pack_bf2(pv[3], pv[2]);
            }
            // PV over 32 tokens (interleaved vt layout, swizzled chunks)
            for (int dt = 0; dt < 4; dt++) {
                int vrow = dt * 16 + l15;
                bf16x8 vb = ld_frag(&sVT[vrow * 64 + (((ns2 * 4 + q) ^ l7) << 3)]);
                o[dt] = mfma16(fa.b, vb, o[dt]);
            }
        }
    }

    // ---- epilogue: normalize + fused per-head merge ----
    rs += __shfl_xor(rs, 16);
    rs += __shfl_xor(rs, 32);
    if (q == 0) sRS[wave][l15] = rs;          // wave-private, in-order
    float invr[4];
    for (int r = 0; r < 4; r++) invr[r] = 1.f / sRS[wave][q * 4 + r];

    unsigned short* pO = &sO[wave * 16 * 72];
    for (int dt = 0; dt < 4; dt++)
        for (int r = 0; r < 4; r++)
            pO[(q * 4 + r) * 72 + dt * 16 + l15] = f2bf(o[dt][r] * invr[r]);

    f32x4 mo[4] = {};
    for (int ks = 0; ks < 2; ks++) {
        bf16x8 af = ld_frag(&pO[l15 * 72 + ks * 32 + q * 8]);
        for (int ns = 0; ns < 4; ns++) {
            bf16x8 wf = ld_frag(&wm_bf[(ns * 16 + l15) * 64 + ks * 32 + q * 8]);
            mo[ns] = mfma16(af, wf, mo[ns]);
        }
    }
    for (int ns = 0; ns < 4; ns++) {
        float bm = b_merge[ns * 16 + l15];
        for (int r = 0; r < 4; r++) {
            long row = rowB + i0w + q * 4 + r;
            tmp_bf[row * INNER_ + colh + ns * 16 + l15] = f2bf(mo[ns][r] + bm);
        }
    }
}

// ---------------------------------------------------------------------------
extern "C" void kernel_launch(void* const* d_in, const int* in_sizes, int n_in,
                              void* d_out, int out_size, void* d_ws, size_t ws_size,
                              hipStream_t stream) {
    const float* x       = (const float*)d_in[0];
    const float* lidar   = (const float*)d_in[1];
    const float* w_qkv   = (const float*)d_in[2];
    const float* w_merge = (const float*)d_in[3];
    const float* b_merge = (const float*)d_in[4];
    const float* w_out   = (const float*)d_in[5];
    const float* b_out   = (const float*)d_in[6];
    const float* conv_w  = (const float*)d_in[7];
    const float* conv_b  = (const float*)d_in[8];

    float* out0      = (float*)d_out;                      // [B,N,DIM]
    float* out_lidar = out0 + (long)B_ * N_ * INNER_;      // [B,N,INNER]

    size_t off = 0;
    auto carve = [&](size_t bytes) {
        void* p = (char*)d_ws + off;
        off += (bytes + 255) & ~(size_t)255;
        return p;
    };
    unsigned short* qkv_bf  = (unsigned short*)carve((size_t)B_ * N_ * 3 * INNER_ * 2);
    unsigned short* lid_bf  = (unsigned short*)carve((size_t)B_ * N_ * INNER_ * 2);
    unsigned short* x_bf    = (unsigned short*)carve((size_t)B_ * N_ * DIM_ * 2);
    unsigned short* wqkv_bf = (unsigned short*)carve((size_t)3 * INNER_ * DIM_ * 2);
    unsigned short* wout_bf = (unsigned short*)carve((size_t)DIM_ * INNER_ * 2);
    unsigned short* wm_bf   = (unsigned short*)carve((size_t)DH_ * DH_ * 2);
    unsigned short* tmp_bf  = (unsigned short*)carve((size_t)B_ * N_ * INNER_ * 2);
    unsigned short* vt_bf   = (unsigned short*)carve((size_t)INNER_ * B_ * N_ * 2);

    k_convert<<<2305, 256, 0, stream>>>(x, lidar, w_qkv, w_merge, w_out,
                                        x_bf, lid_bf, out_lidar,
                                        wqkv_bf, wm_bf, wout_bf);

    k_gemm_qkv<<<dim3(64, 12), 256, 0, stream>>>(
        x_bf, wqkv_bf, qkv_bf, vt_bf, B_ * N_, 3 * INNER_, DIM_);

    k_flash<<<dim3(64, 16), 256, 0, stream>>>(
        qkv_bf, lid_bf, vt_bf, wm_bf, b_merge, conv_w, conv_b, tmp_bf);

    k_gemm_out<<<dim3(64, 8), 256, 0, stream>>>(
        tmp_bf, wout_bf, b_out, out0, B_ * N_, DIM_, INNER_);
}